// Round 1
// baseline (632.288 us; speedup 1.0000x reference)
//
#include <hip/hip_runtime.h>
#include <stdint.h>

typedef unsigned short ushort_t;
typedef __attribute__((ext_vector_type(8))) short s16x8;
typedef __attribute__((ext_vector_type(8))) unsigned short u16x8;
typedef __attribute__((ext_vector_type(4))) float f32x4;

#define AS1C(p) ((const __attribute__((address_space(1))) void*)(p))
#define AS3(p)  ((__attribute__((address_space(3))) void*)(p))

__device__ __forceinline__ ushort_t f2bf(float f) {
  uint32_t u = __float_as_uint(f);
  u += 0x7fffu + ((u >> 16) & 1u);
  return (ushort_t)(u >> 16);
}

// ---------------- convert f32 -> bf16 (vectorized) ----------------
__global__ __launch_bounds__(256) void cvt_kernel(const float* __restrict__ in,
                                                  ushort_t* __restrict__ out, int n4) {
  int i = blockIdx.x * 256 + threadIdx.x;
  if (i >= n4) return;
  const float4 v = ((const float4*)in)[i];
  ushort4 o;
  o.x = f2bf(v.x); o.y = f2bf(v.y); o.z = f2bf(v.z); o.w = f2bf(v.w);
  ((ushort4*)out)[i] = o;
}

// ---------------- bf16 NT GEMM: C[M,N] = A[M,K] * B[N,K]^T + bias ----------------
// 128x128 tile, BK=32, 256 threads (4 waves 2x2), 16x16x32 MFMA, global_load_lds staging.
template <int OUT_BF16>
__global__ __launch_bounds__(256) void gemm_nt(const ushort_t* __restrict__ A,
                                               const ushort_t* __restrict__ B,
                                               const float* __restrict__ bias,
                                               void* __restrict__ C,
                                               int M, int N, int K) {
  __shared__ ushort_t As[128 * 32];
  __shared__ ushort_t Bs[128 * 32];
  const int tid = threadIdx.x;
  const int w = tid >> 6, lane = tid & 63, g = lane >> 4, c = lane & 15;
  const int wm = w >> 1, wn = w & 1;
  const int m0 = blockIdx.y * 128, n0 = blockIdx.x * 128;
  f32x4 acc[4][4] = {};

  for (int k0 = 0; k0 < K; k0 += 32) {
    // stage A,B tiles: 128x32 bf16 = 8KB each; 2 rounds x 256 threads x 16B
#pragma unroll
    for (int r = 0; r < 2; ++r) {
      const int ci = r * 256 + tid;            // 16B chunk id (512 per tile)
      const int row = ci >> 2, col = (ci & 3) << 3;
      const int ldsoff = (r * 256 + w * 64) * 8;  // ushort elems; wave-uniform base
      __builtin_amdgcn_global_load_lds(AS1C(&A[(size_t)(m0 + row) * K + k0 + col]),
                                       AS3(&As[ldsoff]), 16, 0, 0);
      __builtin_amdgcn_global_load_lds(AS1C(&B[(size_t)(n0 + row) * K + k0 + col]),
                                       AS3(&Bs[ldsoff]), 16, 0, 0);
    }
    __syncthreads();
    s16x8 af[4], bfr[4];
#pragma unroll
    for (int mi = 0; mi < 4; ++mi)
      af[mi] = *(const s16x8*)&As[(wm * 64 + mi * 16 + c) * 32 + g * 8];
#pragma unroll
    for (int ni = 0; ni < 4; ++ni)
      bfr[ni] = *(const s16x8*)&Bs[(wn * 64 + ni * 16 + c) * 32 + g * 8];
#pragma unroll
    for (int mi = 0; mi < 4; ++mi)
#pragma unroll
      for (int ni = 0; ni < 4; ++ni)
        acc[mi][ni] = __builtin_amdgcn_mfma_f32_16x16x32_bf16(af[mi], bfr[ni], acc[mi][ni], 0, 0, 0);
    __syncthreads();
  }

  // epilogue: D layout col=lane&15, row=(lane>>4)*4+r
#pragma unroll
  for (int ni = 0; ni < 4; ++ni) {
    const int n = n0 + wn * 64 + ni * 16 + c;
    const float bv = bias[n];
#pragma unroll
    for (int mi = 0; mi < 4; ++mi) {
#pragma unroll
      for (int rr = 0; rr < 4; ++rr) {
        const int m = m0 + wm * 64 + mi * 16 + g * 4 + rr;
        const float val = acc[mi][ni][rr] + bv;
        if (OUT_BF16)
          ((ushort_t*)C)[(size_t)m * N + n] = f2bf(val);
        else
          ((float*)C)[(size_t)m * N + n] = val;
      }
    }
  }
}

// ---------------- V transpose per head: vt[n][dh][i] = v[n][i][dh] ----------------
__global__ __launch_bounds__(256) void transpose_v(const ushort_t* __restrict__ v,
                                                   ushort_t* __restrict__ vt) {
  __shared__ ushort_t T[64][72];  // 144B row stride keeps 16B alignment
  const int n = blockIdx.y, ib = blockIdx.x;
  const int t = threadIdx.x;
  {
    const int row = t >> 2, cb = (t & 3) << 4;
    const ushort_t* src = v + (size_t)n * 65536 + (size_t)(ib * 64 + row) * 64 + cb;
    *(u16x8*)&T[row][cb] = *(const u16x8*)src;
    *(u16x8*)&T[row][cb + 8] = *(const u16x8*)(src + 8);
  }
  __syncthreads();
  {
    const int dh = t >> 2, ibs = (t & 3) << 4;
    u16x8 a, b;
#pragma unroll
    for (int e = 0; e < 8; ++e) { a[e] = T[ibs + e][dh]; b[e] = T[ibs + 8 + e][dh]; }
    ushort_t* dst = vt + (size_t)n * 65536 + (size_t)dh * 1024 + ib * 64 + ibs;
    *(u16x8*)dst = a;
    *(u16x8*)(dst + 8) = b;
  }
}

// ---------------- attention: per (head, 64 q-rows); 2-pass softmax ----------------
__global__ __launch_bounds__(256) void attn_kernel(const ushort_t* __restrict__ q,
                                                   const ushort_t* __restrict__ k,
                                                   const ushort_t* __restrict__ vt,
                                                   float* __restrict__ attn,
                                                   ushort_t* __restrict__ ctx) {
  __shared__ ushort_t P[4][16 * 64];  // per-wave P tile (swizzled)
  const int n = blockIdx.y, qb = blockIdx.x;
  const int tid = threadIdx.x, w = tid >> 6, lane = tid & 63, g = lane >> 4, c = lane & 15;
  const int i0 = qb * 64 + w * 16;
  const ushort_t* qh = q + (size_t)n * 65536;
  const ushort_t* kh = k + (size_t)n * 65536;
  const ushort_t* vh = vt + (size_t)n * 65536;

  // Q fragments (A-operand): lane 16g+c holds Q[i0+c][g*8..g*8+7]
  const s16x8 aq0 = *(const s16x8*)&qh[(i0 + c) * 64 + g * 8];
  const s16x8 aq1 = *(const s16x8*)&qh[(i0 + c) * 64 + 32 + g * 8];

  float m_r[4], l_r[4];
#pragma unroll
  for (int r = 0; r < 4; ++r) { m_r[r] = -1e30f; l_r[r] = 0.f; }

  // ---- pass 1: row max + sum (online) ----
  for (int jt = 0; jt < 16; ++jt) {
    f32x4 s[4];
#pragma unroll
    for (int jn = 0; jn < 4; ++jn) {
      const ushort_t* kr = &kh[(size_t)(jt * 64 + jn * 16 + c) * 64];
      f32x4 z = {0.f, 0.f, 0.f, 0.f};
      z = __builtin_amdgcn_mfma_f32_16x16x32_bf16(aq0, *(const s16x8*)&kr[g * 8], z, 0, 0, 0);
      z = __builtin_amdgcn_mfma_f32_16x16x32_bf16(aq1, *(const s16x8*)&kr[32 + g * 8], z, 0, 0, 0);
      s[jn] = z;
    }
#pragma unroll
    for (int r = 0; r < 4; ++r) {
      float pm = fmaxf(fmaxf(s[0][r], s[1][r]), fmaxf(s[2][r], s[3][r]));
      pm = fmaxf(pm, __shfl_xor(pm, 1));
      pm = fmaxf(pm, __shfl_xor(pm, 2));
      pm = fmaxf(pm, __shfl_xor(pm, 4));
      pm = fmaxf(pm, __shfl_xor(pm, 8));
      const float mnew = fmaxf(m_r[r], 0.5f * pm);
      float ps = __expf(0.5f * s[0][r] - mnew) + __expf(0.5f * s[1][r] - mnew) +
                 __expf(0.5f * s[2][r] - mnew) + __expf(0.5f * s[3][r] - mnew);
      ps += __shfl_xor(ps, 1);
      ps += __shfl_xor(ps, 2);
      ps += __shfl_xor(ps, 4);
      ps += __shfl_xor(ps, 8);
      l_r[r] = l_r[r] * __expf(m_r[r] - mnew) + ps;
      m_r[r] = mnew;
    }
  }

  float il[4];
#pragma unroll
  for (int r = 0; r < 4; ++r) il[r] = 1.f / l_r[r];

  // ---- pass 2: write P, accumulate PV ----
  f32x4 cacc[4] = {};
  ushort_t* pl = &P[w][0];
  float* arow = attn + (size_t)n * 1048576;

  for (int jt = 0; jt < 16; ++jt) {
    f32x4 s[4];
#pragma unroll
    for (int jn = 0; jn < 4; ++jn) {
      const ushort_t* kr = &kh[(size_t)(jt * 64 + jn * 16 + c) * 64];
      f32x4 z = {0.f, 0.f, 0.f, 0.f};
      z = __builtin_amdgcn_mfma_f32_16x16x32_bf16(aq0, *(const s16x8*)&kr[g * 8], z, 0, 0, 0);
      z = __builtin_amdgcn_mfma_f32_16x16x32_bf16(aq1, *(const s16x8*)&kr[32 + g * 8], z, 0, 0, 0);
      s[jn] = z;
    }
#pragma unroll
    for (int jn = 0; jn < 4; ++jn) {
#pragma unroll
      for (int r = 0; r < 4; ++r) {
        const float p = __expf(0.5f * s[jn][r] - m_r[r]) * il[r];
        const int row = 4 * g + r, col = jn * 16 + c;
        arow[(size_t)(i0 + row) * 1024 + jt * 64 + col] = p;
        int bo = (row * 64 + col) * 2;   // byte offset in 128B-row tile
        bo ^= (row & 7) << 4;            // XOR swizzle (G4)
        *(ushort_t*)((char*)pl + bo) = f2bf(p);
      }
    }
    __syncthreads();
#pragma unroll
    for (int ks = 0; ks < 2; ++ks) {
      int rb = (c * 64 + ks * 32 + g * 8) * 2;
      rb ^= (c & 7) << 4;
      const s16x8 pa = *(const s16x8*)((const char*)pl + rb);
#pragma unroll
      for (int dn = 0; dn < 4; ++dn) {
        const s16x8 bv =
            *(const s16x8*)&vh[(size_t)(dn * 16 + c) * 1024 + jt * 64 + ks * 32 + g * 8];
        cacc[dn] = __builtin_amdgcn_mfma_f32_16x16x32_bf16(pa, bv, cacc[dn], 0, 0, 0);
      }
    }
    __syncthreads();
  }

  ushort_t* ch = ctx + (size_t)n * 65536;
#pragma unroll
  for (int dn = 0; dn < 4; ++dn)
#pragma unroll
    for (int r = 0; r < 4; ++r)
      ch[(size_t)(i0 + 4 * g + r) * 64 + dn * 16 + c] = f2bf(cacc[dn][r]);
}

// ---------------- residual + LayerNorm ----------------
__global__ __launch_bounds__(256) void ln_kernel(const float* __restrict__ proj,
                                                 const float* __restrict__ resid,
                                                 const float* __restrict__ gamma,
                                                 const float* __restrict__ beta,
                                                 float* __restrict__ out) {
  __shared__ float sred[4], ssred[4];
  const int row = blockIdx.x, t = threadIdx.x;
  const float4 pv = ((const float4*)(proj + (size_t)row * 1024))[t];
  const float4 rv = ((const float4*)(resid + (size_t)row * 1024))[t];
  float4 x;
  x.x = pv.x + rv.x; x.y = pv.y + rv.y; x.z = pv.z + rv.z; x.w = pv.w + rv.w;
  float s = x.x + x.y + x.z + x.w;
  float ss = x.x * x.x + x.y * x.y + x.z * x.z + x.w * x.w;
#pragma unroll
  for (int msk = 1; msk < 64; msk <<= 1) {
    s += __shfl_xor(s, msk);
    ss += __shfl_xor(ss, msk);
  }
  const int w = t >> 6, lane = t & 63;
  if (lane == 0) { sred[w] = s; ssred[w] = ss; }
  __syncthreads();
  s = sred[0] + sred[1] + sred[2] + sred[3];
  ss = ssred[0] + ssred[1] + ssred[2] + ssred[3];
  const float mu = s * (1.f / 1024.f);
  const float var = ss * (1.f / 1024.f) - mu * mu;
  const float rs = rsqrtf(var + 1e-5f);
  const float4 gm = ((const float4*)gamma)[t];
  const float4 bt = ((const float4*)beta)[t];
  float4 o;
  o.x = (x.x - mu) * rs * gm.x + bt.x;
  o.y = (x.y - mu) * rs * gm.y + bt.y;
  o.z = (x.z - mu) * rs * gm.z + bt.z;
  o.w = (x.w - mu) * rs * gm.w + bt.w;
  ((float4*)(out + (size_t)row * 1024))[t] = o;
}

extern "C" void kernel_launch(void* const* d_in, const int* in_sizes, int n_in,
                              void* d_out, int out_size, void* d_ws, size_t ws_size,
                              hipStream_t stream) {
  const float* key   = (const float*)d_in[0];
  const float* value = (const float*)d_in[1];
  const float* query = (const float*)d_in[2];
  const float* Wq = (const float*)d_in[3];  const float* bq = (const float*)d_in[4];
  const float* Wk = (const float*)d_in[5];  const float* bk = (const float*)d_in[6];
  const float* Wv = (const float*)d_in[7];  const float* bv = (const float*)d_in[8];
  const float* Wo = (const float*)d_in[9];  const float* bo = (const float*)d_in[10];
  const float* gamma = (const float*)d_in[11];
  const float* beta  = (const float*)d_in[12];

  // workspace layout (69.2 MB)
  char* ws = (char*)d_ws;
  ushort_t* q_   = (ushort_t*)(ws + 0);
  ushort_t* k_   = (ushort_t*)(ws + 16777216);
  ushort_t* vt_  = (ushort_t*)(ws + 33554432);
  ushort_t* ctx_ = (ushort_t*)(ws + 50331648);
  ushort_t* wo_  = (ushort_t*)(ws + 67108864);
  float*    proj_ = (float*)(ws + 0);  // aliases q_,k_ (dead after attention)

  // d_out layout: out [8388608 f32] then attn [134217728 f32].
  // The attn region is free scratch until attn_kernel writes it.
  char* o8 = (char*)d_out;
  float*    outp  = (float*)o8;
  float*    attnp = (float*)(o8 + 33554432);
  ushort_t* xq  = (ushort_t*)(o8 + 33554432);
  ushort_t* xk  = (ushort_t*)(o8 + 50331648);
  ushort_t* xv  = (ushort_t*)(o8 + 67108864);
  ushort_t* wq_ = (ushort_t*)(o8 + 83886080);
  ushort_t* wk_ = (ushort_t*)(o8 + 85983232);
  ushort_t* wv_ = (ushort_t*)(o8 + 88080384);
  ushort_t* v_  = (ushort_t*)(o8 + 90177536);

  const int n4x = 8192 * 1024 / 4;   // activations
  const int n4w = 1024 * 1024 / 4;   // weights
  cvt_kernel<<<n4x / 256, 256, 0, stream>>>(query, xq, n4x);
  cvt_kernel<<<n4x / 256, 256, 0, stream>>>(key,   xk, n4x);
  cvt_kernel<<<n4x / 256, 256, 0, stream>>>(value, xv, n4x);
  cvt_kernel<<<n4w / 256, 256, 0, stream>>>(Wq, wq_, n4w);
  cvt_kernel<<<n4w / 256, 256, 0, stream>>>(Wk, wk_, n4w);
  cvt_kernel<<<n4w / 256, 256, 0, stream>>>(Wv, wv_, n4w);
  cvt_kernel<<<n4w / 256, 256, 0, stream>>>(Wo, wo_, n4w);

  dim3 gg(8, 64);
  gemm_nt<1><<<gg, 256, 0, stream>>>(xq, wq_, bq, q_, 8192, 1024, 1024);
  gemm_nt<1><<<gg, 256, 0, stream>>>(xk, wk_, bk, k_, 8192, 1024, 1024);
  gemm_nt<1><<<gg, 256, 0, stream>>>(xv, wv_, bv, v_, 8192, 1024, 1024);

  transpose_v<<<dim3(16, 128), 256, 0, stream>>>(v_, vt_);

  attn_kernel<<<dim3(16, 128), 256, 0, stream>>>(q_, k_, vt_, attnp, ctx_);

  gemm_nt<0><<<gg, 256, 0, stream>>>(ctx_, wo_, bo, proj_, 8192, 1024, 1024);

  ln_kernel<<<8192, 256, 0, stream>>>(proj_, query, gamma, beta, outp);
}

// Round 2
// 611.343 us; speedup vs baseline: 1.0343x; 1.0343x over previous
//
#include <hip/hip_runtime.h>
#include <stdint.h>

typedef unsigned short ushort_t;
typedef __attribute__((ext_vector_type(8))) short s16x8;
typedef __attribute__((ext_vector_type(8))) unsigned short u16x8;
typedef __attribute__((ext_vector_type(4))) float f32x4;

#define AS1C(p) ((const __attribute__((address_space(1))) void*)(p))
#define AS3(p)  ((__attribute__((address_space(3))) void*)(p))

// per-wave LDS fence: own-wave ds_write -> ds_read ordering without s_barrier
#define WAVE_LDS_FENCE()                                    \
  do {                                                      \
    asm volatile("s_waitcnt lgkmcnt(0)" ::: "memory");      \
    __builtin_amdgcn_sched_barrier(0);                      \
  } while (0)

__device__ __forceinline__ ushort_t f2bf(float f) {
  uint32_t u = __float_as_uint(f);
  u += 0x7fffu + ((u >> 16) & 1u);
  return (ushort_t)(u >> 16);
}

// ---------------- convert f32 -> bf16 (vectorized) ----------------
__global__ __launch_bounds__(256) void cvt_kernel(const float* __restrict__ in,
                                                  ushort_t* __restrict__ out, int n4) {
  int i = blockIdx.x * 256 + threadIdx.x;
  if (i >= n4) return;
  const float4 v = ((const float4*)in)[i];
  ushort4 o;
  o.x = f2bf(v.x); o.y = f2bf(v.y); o.z = f2bf(v.z); o.w = f2bf(v.w);
  ((ushort4*)out)[i] = o;
}

// ---------------- bf16 NT GEMM: C[M,N] = A[M,K] * B[N,K]^T + bias ----------------
template <int OUT_BF16>
__global__ __launch_bounds__(256) void gemm_nt(const ushort_t* __restrict__ A,
                                               const ushort_t* __restrict__ B,
                                               const float* __restrict__ bias,
                                               void* __restrict__ C,
                                               int M, int N, int K) {
  __shared__ ushort_t As[128 * 32];
  __shared__ ushort_t Bs[128 * 32];
  const int tid = threadIdx.x;
  const int w = tid >> 6, lane = tid & 63, g = lane >> 4, c = lane & 15;
  const int wm = w >> 1, wn = w & 1;
  const int m0 = blockIdx.y * 128, n0 = blockIdx.x * 128;
  f32x4 acc[4][4] = {};

  for (int k0 = 0; k0 < K; k0 += 32) {
#pragma unroll
    for (int r = 0; r < 2; ++r) {
      const int ci = r * 256 + tid;
      const int row = ci >> 2, col = (ci & 3) << 3;
      const int ldsoff = (r * 256 + w * 64) * 8;
      __builtin_amdgcn_global_load_lds(AS1C(&A[(size_t)(m0 + row) * K + k0 + col]),
                                       AS3(&As[ldsoff]), 16, 0, 0);
      __builtin_amdgcn_global_load_lds(AS1C(&B[(size_t)(n0 + row) * K + k0 + col]),
                                       AS3(&Bs[ldsoff]), 16, 0, 0);
    }
    __syncthreads();
    s16x8 af[4], bfr[4];
#pragma unroll
    for (int mi = 0; mi < 4; ++mi)
      af[mi] = *(const s16x8*)&As[(wm * 64 + mi * 16 + c) * 32 + g * 8];
#pragma unroll
    for (int ni = 0; ni < 4; ++ni)
      bfr[ni] = *(const s16x8*)&Bs[(wn * 64 + ni * 16 + c) * 32 + g * 8];
#pragma unroll
    for (int mi = 0; mi < 4; ++mi)
#pragma unroll
      for (int ni = 0; ni < 4; ++ni)
        acc[mi][ni] = __builtin_amdgcn_mfma_f32_16x16x32_bf16(af[mi], bfr[ni], acc[mi][ni], 0, 0, 0);
    __syncthreads();
  }

#pragma unroll
  for (int ni = 0; ni < 4; ++ni) {
    const int n = n0 + wn * 64 + ni * 16 + c;
    const float bv = bias[n];
#pragma unroll
    for (int mi = 0; mi < 4; ++mi) {
#pragma unroll
      for (int rr = 0; rr < 4; ++rr) {
        const int m = m0 + wm * 64 + mi * 16 + g * 4 + rr;
        const float val = acc[mi][ni][rr] + bv;
        if (OUT_BF16)
          ((ushort_t*)C)[(size_t)m * N + n] = f2bf(val);
        else
          ((float*)C)[(size_t)m * N + n] = val;
      }
    }
  }
}

// ---------------- V transpose per head: vt[n][dh][i] = v[n][i][dh] ----------------
__global__ __launch_bounds__(256) void transpose_v(const ushort_t* __restrict__ v,
                                                   ushort_t* __restrict__ vt) {
  __shared__ ushort_t T[64][72];
  const int n = blockIdx.y, ib = blockIdx.x;
  const int t = threadIdx.x;
  {
    const int row = t >> 2, cb = (t & 3) << 4;
    const ushort_t* src = v + (size_t)n * 65536 + (size_t)(ib * 64 + row) * 64 + cb;
    *(u16x8*)&T[row][cb] = *(const u16x8*)src;
    *(u16x8*)&T[row][cb + 8] = *(const u16x8*)(src + 8);
  }
  __syncthreads();
  {
    const int dh = t >> 2, ibs = (t & 3) << 4;
    u16x8 a, b;
#pragma unroll
    for (int e = 0; e < 8; ++e) { a[e] = T[ibs + e][dh]; b[e] = T[ibs + 8 + e][dh]; }
    ushort_t* dst = vt + (size_t)n * 65536 + (size_t)dh * 1024 + ib * 64 + ibs;
    *(u16x8*)dst = a;
    *(u16x8*)(dst + 8) = b;
  }
}

// ---------------- attention ----------------
// grid: 2048 linear blocks, XCD-swizzled so all 16 q-blocks of a head land on
// one XCD (head's K/V then L2-resident on that XCD: 16 heads x 256KB = 4MB = L2).
// Per-wave independent (no __syncthreads): 16 q-rows per wave.
// Pass 1: lane-local online softmax (no cross-lane ops in the loop).
// Pass 2: recompute scores, stage P in per-wave f32 LDS tile (XOR-swizzled),
//         coalesced float4 global stores + bf16 fragment rebuild for PV MFMA.
__global__ __launch_bounds__(256) void attn_kernel(const ushort_t* __restrict__ q,
                                                   const ushort_t* __restrict__ k,
                                                   const ushort_t* __restrict__ vt,
                                                   float* __restrict__ attn,
                                                   ushort_t* __restrict__ ctx) {
  __shared__ float Pf[4][1024];  // per-wave 16x64 f32 tile, XOR-swizzled
  const int wg = blockIdx.x;
  const int idx = ((wg & 7) << 8) | (wg >> 3);  // XCD swizzle (bijective, 2048=8*256)
  const int n = idx >> 4, qb = idx & 15;
  const int tid = threadIdx.x, w = tid >> 6, lane = tid & 63, g = lane >> 4, c = lane & 15;
  const int i0 = qb * 64 + w * 16;
  const ushort_t* qh = q + (size_t)n * 65536;
  const ushort_t* kh = k + (size_t)n * 65536;
  const ushort_t* vh = vt + (size_t)n * 65536;
  char* pw = (char*)&Pf[w][0];

  // Q fragments (A-operand): lane 16g+c holds Q[i0+c][g*8..g*8+7]
  const s16x8 aq0 = *(const s16x8*)&qh[(i0 + c) * 64 + g * 8];
  const s16x8 aq1 = *(const s16x8*)&qh[(i0 + c) * 64 + 32 + g * 8];

  // ---- pass 1: lane-local online max+sum over this lane's column slices ----
  float m_p[4], l_p[4];
#pragma unroll
  for (int r = 0; r < 4; ++r) { m_p[r] = -1e30f; l_p[r] = 0.f; }

  for (int jt = 0; jt < 16; ++jt) {
    f32x4 s[4];
#pragma unroll
    for (int jn = 0; jn < 4; ++jn) {
      const ushort_t* kr = &kh[(size_t)(jt * 64 + jn * 16 + c) * 64];
      f32x4 z = {0.f, 0.f, 0.f, 0.f};
      z = __builtin_amdgcn_mfma_f32_16x16x32_bf16(aq0, *(const s16x8*)&kr[g * 8], z, 0, 0, 0);
      z = __builtin_amdgcn_mfma_f32_16x16x32_bf16(aq1, *(const s16x8*)&kr[32 + g * 8], z, 0, 0, 0);
      s[jn] = z * 0.5f;  // fold SCALE
    }
#pragma unroll
    for (int r = 0; r < 4; ++r) {
      const float pm = fmaxf(fmaxf(s[0][r], s[1][r]), fmaxf(s[2][r], s[3][r]));
      const float mn = fmaxf(m_p[r], pm);
      l_p[r] = l_p[r] * __expf(m_p[r] - mn) + __expf(s[0][r] - mn) + __expf(s[1][r] - mn) +
               __expf(s[2][r] - mn) + __expf(s[3][r] - mn);
      m_p[r] = mn;
    }
  }

  // merge the 16 lanes of each row group (once, after the sweep)
  float bias_r[4];
#pragma unroll
  for (int r = 0; r < 4; ++r) {
    float m = m_p[r], l = l_p[r];
#pragma unroll
    for (int mask = 1; mask < 16; mask <<= 1) {
      const float mo = __shfl_xor(m, mask);
      const float lo = __shfl_xor(l, mask);
      const float mn = fmaxf(m, mo);
      l = l * __expf(m - mn) + lo * __expf(mo - mn);
      m = mn;
    }
    bias_r[r] = m + __logf(l);  // p = exp(0.5*s - bias)
  }

  // ---- pass 2: recompute, stage P in LDS, coalesced stores + PV ----
  f32x4 cacc[4] = {};
  float* arow = attn + (size_t)n * 1048576;

  for (int jt = 0; jt < 16; ++jt) {
    f32x4 s[4];
#pragma unroll
    for (int jn = 0; jn < 4; ++jn) {
      const ushort_t* kr = &kh[(size_t)(jt * 64 + jn * 16 + c) * 64];
      f32x4 z = {0.f, 0.f, 0.f, 0.f};
      z = __builtin_amdgcn_mfma_f32_16x16x32_bf16(aq0, *(const s16x8*)&kr[g * 8], z, 0, 0, 0);
      z = __builtin_amdgcn_mfma_f32_16x16x32_bf16(aq1, *(const s16x8*)&kr[32 + g * 8], z, 0, 0, 0);
      s[jn] = z;
    }
    // write P tile (f32, swizzled): row=4g+r, col=jn*16+c
#pragma unroll
    for (int jn = 0; jn < 4; ++jn) {
#pragma unroll
      for (int r = 0; r < 4; ++r) {
        const float p = __expf(fmaf(0.5f, s[jn][r], -bias_r[r]));
        const int row = 4 * g + r, col = jn * 16 + c;
        const int A = (row << 8) + (col << 2);
        *(float*)(pw + (A ^ ((row & 7) << 4))) = p;
      }
    }
    WAVE_LDS_FENCE();
    // coalesced global stores: 4x float4 per lane
#pragma unroll
    for (int e = 0; e < 4; ++e) {
      const int row = (lane >> 4) + 4 * e;
      const int A = (row << 8) + ((lane & 15) << 4);
      const f32x4 pv = *(const f32x4*)(pw + (A ^ ((row & 7) << 4)));
      *(f32x4*)&arow[(size_t)(i0 + row) * 1024 + jt * 64 + ((lane & 15) << 2)] = pv;
    }
    // PV: rebuild bf16 A-fragment from the f32 tile; B from pre-transposed V
#pragma unroll
    for (int ks = 0; ks < 2; ++ks) {
      const int base = (c << 8) + (ks << 7) + (g << 5);
      const int sw = (c & 7) << 4;
      const f32x4 fa = *(const f32x4*)(pw + (base ^ sw));
      const f32x4 fb = *(const f32x4*)(pw + ((base + 16) ^ sw));
      s16x8 pa;
#pragma unroll
      for (int e = 0; e < 4; ++e) {
        pa[e] = (short)f2bf(fa[e]);
        pa[4 + e] = (short)f2bf(fb[e]);
      }
#pragma unroll
      for (int dn = 0; dn < 4; ++dn) {
        const s16x8 bv =
            *(const s16x8*)&vh[(size_t)(dn * 16 + c) * 1024 + jt * 64 + ks * 32 + g * 8];
        cacc[dn] = __builtin_amdgcn_mfma_f32_16x16x32_bf16(pa, bv, cacc[dn], 0, 0, 0);
      }
    }
    WAVE_LDS_FENCE();  // order this jt's reads before next jt's writes
  }

  ushort_t* ch = ctx + (size_t)n * 65536;
#pragma unroll
  for (int dn = 0; dn < 4; ++dn)
#pragma unroll
    for (int r = 0; r < 4; ++r)
      ch[(size_t)(i0 + 4 * g + r) * 64 + dn * 16 + c] = f2bf(cacc[dn][r]);
}

// ---------------- residual + LayerNorm ----------------
__global__ __launch_bounds__(256) void ln_kernel(const float* __restrict__ proj,
                                                 const float* __restrict__ resid,
                                                 const float* __restrict__ gamma,
                                                 const float* __restrict__ beta,
                                                 float* __restrict__ out) {
  __shared__ float sred[4], ssred[4];
  const int row = blockIdx.x, t = threadIdx.x;
  const float4 pv = ((const float4*)(proj + (size_t)row * 1024))[t];
  const float4 rv = ((const float4*)(resid + (size_t)row * 1024))[t];
  float4 x;
  x.x = pv.x + rv.x; x.y = pv.y + rv.y; x.z = pv.z + rv.z; x.w = pv.w + rv.w;
  float s = x.x + x.y + x.z + x.w;
  float ss = x.x * x.x + x.y * x.y + x.z * x.z + x.w * x.w;
#pragma unroll
  for (int msk = 1; msk < 64; msk <<= 1) {
    s += __shfl_xor(s, msk);
    ss += __shfl_xor(ss, msk);
  }
  const int w = t >> 6, lane = t & 63;
  if (lane == 0) { sred[w] = s; ssred[w] = ss; }
  __syncthreads();
  s = sred[0] + sred[1] + sred[2] + sred[3];
  ss = ssred[0] + ssred[1] + ssred[2] + ssred[3];
  const float mu = s * (1.f / 1024.f);
  const float var = ss * (1.f / 1024.f) - mu * mu;
  const float rs = rsqrtf(var + 1e-5f);
  const float4 gm = ((const float4*)gamma)[t];
  const float4 bt = ((const float4*)beta)[t];
  float4 o;
  o.x = (x.x - mu) * rs * gm.x + bt.x;
  o.y = (x.y - mu) * rs * gm.y + bt.y;
  o.z = (x.z - mu) * rs * gm.z + bt.z;
  o.w = (x.w - mu) * rs * gm.w + bt.w;
  ((float4*)(out + (size_t)row * 1024))[t] = o;
}

extern "C" void kernel_launch(void* const* d_in, const int* in_sizes, int n_in,
                              void* d_out, int out_size, void* d_ws, size_t ws_size,
                              hipStream_t stream) {
  const float* key   = (const float*)d_in[0];
  const float* value = (const float*)d_in[1];
  const float* query = (const float*)d_in[2];
  const float* Wq = (const float*)d_in[3];  const float* bq = (const float*)d_in[4];
  const float* Wk = (const float*)d_in[5];  const float* bk = (const float*)d_in[6];
  const float* Wv = (const float*)d_in[7];  const float* bv = (const float*)d_in[8];
  const float* Wo = (const float*)d_in[9];  const float* bo = (const float*)d_in[10];
  const float* gamma = (const float*)d_in[11];
  const float* beta  = (const float*)d_in[12];

  char* ws = (char*)d_ws;
  ushort_t* q_   = (ushort_t*)(ws + 0);
  ushort_t* k_   = (ushort_t*)(ws + 16777216);
  ushort_t* vt_  = (ushort_t*)(ws + 33554432);
  ushort_t* ctx_ = (ushort_t*)(ws + 50331648);
  ushort_t* wo_  = (ushort_t*)(ws + 67108864);
  float*    proj_ = (float*)(ws + 0);  // aliases q_,k_ (dead after attention)

  char* o8 = (char*)d_out;
  float*    outp  = (float*)o8;
  float*    attnp = (float*)(o8 + 33554432);
  ushort_t* xq  = (ushort_t*)(o8 + 33554432);
  ushort_t* xk  = (ushort_t*)(o8 + 50331648);
  ushort_t* xv  = (ushort_t*)(o8 + 67108864);
  ushort_t* wq_ = (ushort_t*)(o8 + 83886080);
  ushort_t* wk_ = (ushort_t*)(o8 + 85983232);
  ushort_t* wv_ = (ushort_t*)(o8 + 88080384);
  ushort_t* v_  = (ushort_t*)(o8 + 90177536);

  const int n4x = 8192 * 1024 / 4;
  const int n4w = 1024 * 1024 / 4;
  cvt_kernel<<<n4x / 256, 256, 0, stream>>>(query, xq, n4x);
  cvt_kernel<<<n4x / 256, 256, 0, stream>>>(key,   xk, n4x);
  cvt_kernel<<<n4x / 256, 256, 0, stream>>>(value, xv, n4x);
  cvt_kernel<<<n4w / 256, 256, 0, stream>>>(Wq, wq_, n4w);
  cvt_kernel<<<n4w / 256, 256, 0, stream>>>(Wk, wk_, n4w);
  cvt_kernel<<<n4w / 256, 256, 0, stream>>>(Wv, wv_, n4w);
  cvt_kernel<<<n4w / 256, 256, 0, stream>>>(Wo, wo_, n4w);

  dim3 gg(8, 64);
  gemm_nt<1><<<gg, 256, 0, stream>>>(xq, wq_, bq, q_, 8192, 1024, 1024);
  gemm_nt<1><<<gg, 256, 0, stream>>>(xk, wk_, bk, k_, 8192, 1024, 1024);
  gemm_nt<1><<<gg, 256, 0, stream>>>(xv, wv_, bv, v_, 8192, 1024, 1024);

  transpose_v<<<dim3(16, 128), 256, 0, stream>>>(v_, vt_);

  attn_kernel<<<2048, 256, 0, stream>>>(q_, k_, vt_, attnp, ctx_);

  gemm_nt<0><<<gg, 256, 0, stream>>>(ctx_, wo_, bo, proj_, 8192, 1024, 1024);

  ln_kernel<<<8192, 256, 0, stream>>>(proj_, query, gamma, beta, outp);
}

// Round 3
// 392.573 us; speedup vs baseline: 1.6106x; 1.5573x over previous
//
#include <hip/hip_runtime.h>
#include <stdint.h>

typedef unsigned short ushort_t;
typedef __attribute__((ext_vector_type(8))) short s16x8;
typedef __attribute__((ext_vector_type(8))) unsigned short u16x8;
typedef __attribute__((ext_vector_type(4))) unsigned short u16x4;
typedef __attribute__((ext_vector_type(4))) float f32x4;

#define AS1C(p) ((const __attribute__((address_space(1))) void*)(p))
#define AS3(p)  ((__attribute__((address_space(3))) void*)(p))

// per-wave LDS fence: own-wave ds_write -> ds_read ordering without s_barrier
#define WAVE_LDS_FENCE()                                    \
  do {                                                      \
    asm volatile("s_waitcnt lgkmcnt(0)" ::: "memory");      \
    __builtin_amdgcn_sched_barrier(0);                      \
  } while (0)

__device__ __forceinline__ ushort_t f2bf(float f) {
  uint32_t u = __float_as_uint(f);
  u += 0x7fffu + ((u >> 16) & 1u);
  return (ushort_t)(u >> 16);
}
__device__ __forceinline__ float bf2f(ushort_t h) {
  return __uint_as_float(((uint32_t)h) << 16);
}

// ---------------- convert f32 -> bf16 (vectorized) ----------------
__global__ __launch_bounds__(256) void cvt_kernel(const float* __restrict__ in,
                                                  ushort_t* __restrict__ out, int n4) {
  int i = blockIdx.x * 256 + threadIdx.x;
  if (i >= n4) return;
  const float4 v = ((const float4*)in)[i];
  ushort4 o;
  o.x = f2bf(v.x); o.y = f2bf(v.y); o.z = f2bf(v.z); o.w = f2bf(v.w);
  ((ushort4*)out)[i] = o;
}

// ---------------- bf16 NT GEMM: C[M,N] = A[M,K] * B[N,K]^T + bias ----------------
template <int OUT_BF16>
__global__ __launch_bounds__(256) void gemm_nt(const ushort_t* __restrict__ A,
                                               const ushort_t* __restrict__ B,
                                               const float* __restrict__ bias,
                                               void* __restrict__ C,
                                               int M, int N, int K) {
  __shared__ ushort_t As[128 * 32];
  __shared__ ushort_t Bs[128 * 32];
  const int tid = threadIdx.x;
  const int w = tid >> 6, lane = tid & 63, g = lane >> 4, c = lane & 15;
  const int wm = w >> 1, wn = w & 1;
  const int m0 = blockIdx.y * 128, n0 = blockIdx.x * 128;
  f32x4 acc[4][4] = {};

  for (int k0 = 0; k0 < K; k0 += 32) {
#pragma unroll
    for (int r = 0; r < 2; ++r) {
      const int ci = r * 256 + tid;
      const int row = ci >> 2, col = (ci & 3) << 3;
      const int ldsoff = (r * 256 + w * 64) * 8;
      __builtin_amdgcn_global_load_lds(AS1C(&A[(size_t)(m0 + row) * K + k0 + col]),
                                       AS3(&As[ldsoff]), 16, 0, 0);
      __builtin_amdgcn_global_load_lds(AS1C(&B[(size_t)(n0 + row) * K + k0 + col]),
                                       AS3(&Bs[ldsoff]), 16, 0, 0);
    }
    __syncthreads();
    s16x8 af[4], bfr[4];
#pragma unroll
    for (int mi = 0; mi < 4; ++mi)
      af[mi] = *(const s16x8*)&As[(wm * 64 + mi * 16 + c) * 32 + g * 8];
#pragma unroll
    for (int ni = 0; ni < 4; ++ni)
      bfr[ni] = *(const s16x8*)&Bs[(wn * 64 + ni * 16 + c) * 32 + g * 8];
#pragma unroll
    for (int mi = 0; mi < 4; ++mi)
#pragma unroll
      for (int ni = 0; ni < 4; ++ni)
        acc[mi][ni] = __builtin_amdgcn_mfma_f32_16x16x32_bf16(af[mi], bfr[ni], acc[mi][ni], 0, 0, 0);
    __syncthreads();
  }

#pragma unroll
  for (int ni = 0; ni < 4; ++ni) {
    const int n = n0 + wn * 64 + ni * 16 + c;
    const float bv = bias[n];
#pragma unroll
    for (int mi = 0; mi < 4; ++mi) {
#pragma unroll
      for (int rr = 0; rr < 4; ++rr) {
        const int m = m0 + wm * 64 + mi * 16 + g * 4 + rr;
        const float val = acc[mi][ni][rr] + bv;
        if (OUT_BF16)
          ((ushort_t*)C)[(size_t)m * N + n] = f2bf(val);
        else
          ((float*)C)[(size_t)m * N + n] = val;
      }
    }
  }
}

// ---------------- V transpose per head: vt[n][dh][i] = v[n][i][dh] ----------------
__global__ __launch_bounds__(256) void transpose_v(const ushort_t* __restrict__ v,
                                                   ushort_t* __restrict__ vt) {
  __shared__ ushort_t T[64][72];
  const int n = blockIdx.y, ib = blockIdx.x;
  const int t = threadIdx.x;
  {
    const int row = t >> 2, cb = (t & 3) << 4;
    const ushort_t* src = v + (size_t)n * 65536 + (size_t)(ib * 64 + row) * 64 + cb;
    *(u16x8*)&T[row][cb] = *(const u16x8*)src;
    *(u16x8*)&T[row][cb + 8] = *(const u16x8*)(src + 8);
  }
  __syncthreads();
  {
    const int dh = t >> 2, ibs = (t & 3) << 4;
    u16x8 a, b;
#pragma unroll
    for (int e = 0; e < 8; ++e) { a[e] = T[ibs + e][dh]; b[e] = T[ibs + 8 + e][dh]; }
    ushort_t* dst = vt + (size_t)n * 65536 + (size_t)dh * 1024 + ib * 64 + ibs;
    *(u16x8*)dst = a;
    *(u16x8*)(dst + 8) = b;
  }
}

// ---------------- attention ----------------
// XCD-swizzled grid: all 16 q-blocks of a head on one XCD (K/V L2-resident).
// K/V tiles double-buffered in LDS via global_load_lds (pre-swizzled source,
// XOR-swizzled ds_read: rule #21). P tile per-wave in bf16 LDS feeds both the
// coalesced f32 attn stores and the PV A-fragment. One barrier per jt.
__global__ __launch_bounds__(256) void attn_kernel(const ushort_t* __restrict__ q,
                                                   const ushort_t* __restrict__ k,
                                                   const ushort_t* __restrict__ vt,
                                                   float* __restrict__ attn,
                                                   ushort_t* __restrict__ ctx) {
  __shared__ ushort_t Kb[2][64 * 64];
  __shared__ ushort_t Vb[2][64 * 64];
  __shared__ ushort_t Pb[4][16 * 64];
  const int wg = blockIdx.x;
  const int idx = ((wg & 7) << 8) | (wg >> 3);  // XCD swizzle (bijective, 2048=8*256)
  const int n = idx >> 4, qb = idx & 15;
  const int tid = threadIdx.x, w = tid >> 6, lane = tid & 63, g = lane >> 4, c = lane & 15;
  const int i0 = qb * 64 + w * 16;
  const ushort_t* qh = q + (size_t)n * 65536;
  const char* khb = (const char*)(k + (size_t)n * 65536);
  const char* vhb = (const char*)(vt + (size_t)n * 65536);
  char* pwb = (char*)&Pb[w][0];

  // staging geometry: wave w stages tile rows [w*16, w*16+16) in 2 instrs of 8 rows
  const int r0 = w * 16 + (lane >> 3);           // rows for instr 0
  const int csw = (((lane & 7) ^ (lane >> 3)) << 4);  // pre-swizzled byte-in-row

#define STAGE_K(buf, jt_)                                                                   \
  do {                                                                                      \
    __builtin_amdgcn_global_load_lds(AS1C(khb + ((size_t)(jt_)*64 + r0) * 128 + csw),       \
                                     AS3(&Kb[buf][(w * 2 + 0) * 512]), 16, 0, 0);           \
    __builtin_amdgcn_global_load_lds(AS1C(khb + ((size_t)(jt_)*64 + r0 + 8) * 128 + csw),   \
                                     AS3(&Kb[buf][(w * 2 + 1) * 512]), 16, 0, 0);           \
  } while (0)
#define STAGE_V(buf, jt_)                                                                   \
  do {                                                                                      \
    __builtin_amdgcn_global_load_lds(AS1C(vhb + (size_t)r0 * 2048 + (jt_)*128 + csw),       \
                                     AS3(&Vb[buf][(w * 2 + 0) * 512]), 16, 0, 0);           \
    __builtin_amdgcn_global_load_lds(AS1C(vhb + (size_t)(r0 + 8) * 2048 + (jt_)*128 + csw), \
                                     AS3(&Vb[buf][(w * 2 + 1) * 512]), 16, 0, 0);           \
  } while (0)
// fragment reads (row & 7 == c & 7 for all uses below)
#define KFRAG(buf, jn, h)                                                     \
  (*(const s16x8*)((const char*)&Kb[buf][0] +                                 \
                   (((((jn)*16 + c) * 128 + (h)*64 + g * 16)) ^ ((c & 7) << 4))))
#define VFRAG(buf, dn, ks_)                                                   \
  (*(const s16x8*)((const char*)&Vb[buf][0] +                                 \
                   (((((dn)*16 + c) * 128 + (ks_)*64 + g * 16)) ^ ((c & 7) << 4))))

  // Q fragments (A-operand): lane 16g+c holds Q[i0+c][g*8..g*8+7]
  const s16x8 aq0 = *(const s16x8*)&qh[(i0 + c) * 64 + g * 8];
  const s16x8 aq1 = *(const s16x8*)&qh[(i0 + c) * 64 + 32 + g * 8];

  // ---- pass 1: lane-local online max+sum ----
  float m_p[4], l_p[4];
#pragma unroll
  for (int r = 0; r < 4; ++r) { m_p[r] = -1e30f; l_p[r] = 0.f; }

  STAGE_K(0, 0);
  __syncthreads();
  for (int jt = 0; jt < 16; ++jt) {
    const int cur = jt & 1;
    if (jt + 1 < 16) STAGE_K((jt + 1) & 1, jt + 1);
    f32x4 s[4];
    __builtin_amdgcn_s_setprio(1);
#pragma unroll
    for (int jn = 0; jn < 4; ++jn) {
      f32x4 z = {0.f, 0.f, 0.f, 0.f};
      z = __builtin_amdgcn_mfma_f32_16x16x32_bf16(aq0, KFRAG(cur, jn, 0), z, 0, 0, 0);
      z = __builtin_amdgcn_mfma_f32_16x16x32_bf16(aq1, KFRAG(cur, jn, 1), z, 0, 0, 0);
      s[jn] = z * 0.5f;
    }
    __builtin_amdgcn_s_setprio(0);
#pragma unroll
    for (int r = 0; r < 4; ++r) {
      const float pm = fmaxf(fmaxf(s[0][r], s[1][r]), fmaxf(s[2][r], s[3][r]));
      const float mn = fmaxf(m_p[r], pm);
      l_p[r] = l_p[r] * __expf(m_p[r] - mn) + __expf(s[0][r] - mn) + __expf(s[1][r] - mn) +
               __expf(s[2][r] - mn) + __expf(s[3][r] - mn);
      m_p[r] = mn;
    }
    __syncthreads();
  }

  // merge the 16 lanes of each row group
  float bias_r[4];
#pragma unroll
  for (int r = 0; r < 4; ++r) {
    float m = m_p[r], l = l_p[r];
#pragma unroll
    for (int mask = 1; mask < 16; mask <<= 1) {
      const float mo = __shfl_xor(m, mask);
      const float lo = __shfl_xor(l, mask);
      const float mn = fmaxf(m, mo);
      l = l * __expf(m - mn) + lo * __expf(mo - mn);
      m = mn;
    }
    bias_r[r] = m + __logf(l);  // p = exp(0.5*s - bias)
  }

  // ---- pass 2 ----
  f32x4 cacc[4] = {};
  float* arow = attn + (size_t)n * 1048576;

  STAGE_K(0, 0);
  STAGE_V(0, 0);
  __syncthreads();
  for (int jt = 0; jt < 16; ++jt) {
    const int cur = jt & 1;
    if (jt + 1 < 16) { STAGE_K((jt + 1) & 1, jt + 1); STAGE_V((jt + 1) & 1, jt + 1); }
    f32x4 s[4];
    __builtin_amdgcn_s_setprio(1);
#pragma unroll
    for (int jn = 0; jn < 4; ++jn) {
      f32x4 z = {0.f, 0.f, 0.f, 0.f};
      z = __builtin_amdgcn_mfma_f32_16x16x32_bf16(aq0, KFRAG(cur, jn, 0), z, 0, 0, 0);
      z = __builtin_amdgcn_mfma_f32_16x16x32_bf16(aq1, KFRAG(cur, jn, 1), z, 0, 0, 0);
      s[jn] = z;
    }
    __builtin_amdgcn_s_setprio(0);
    // write P tile (bf16, swizzled): row=4g+r, col=jn*16+c
#pragma unroll
    for (int jn = 0; jn < 4; ++jn) {
#pragma unroll
      for (int r = 0; r < 4; ++r) {
        const float p = __expf(fmaf(0.5f, s[jn][r], -bias_r[r]));
        const int row = 4 * g + r;
        const int A = (row << 7) + ((jn * 16 + c) << 1);
        *(ushort_t*)(pwb + (A ^ ((row & 7) << 4))) = f2bf(p);
      }
    }
    WAVE_LDS_FENCE();
    // coalesced attn stores: lane -> row g+4e, cols c*4..c*4+3
#pragma unroll
    for (int e = 0; e < 4; ++e) {
      const int row = g + 4 * e;
      const int A = (row << 7) + (c << 3);
      const u16x4 hv = *(const u16x4*)(pwb + (A ^ ((row & 7) << 4)));
      f32x4 fv;
#pragma unroll
      for (int t2 = 0; t2 < 4; ++t2) fv[t2] = bf2f(hv[t2]);
      *(f32x4*)&arow[(size_t)(i0 + row) * 1024 + jt * 64 + c * 4] = fv;
    }
    // PV: A-fragment straight from bf16 P tile; B from staged V tile
    __builtin_amdgcn_s_setprio(1);
#pragma unroll
    for (int ks = 0; ks < 2; ++ks) {
      const int A = (c << 7) + (ks << 6) + (g << 4);
      const s16x8 pa = *(const s16x8*)(pwb + (A ^ ((c & 7) << 4)));
#pragma unroll
      for (int dn = 0; dn < 4; ++dn)
        cacc[dn] = __builtin_amdgcn_mfma_f32_16x16x32_bf16(pa, VFRAG(cur, dn, ks), cacc[dn], 0, 0, 0);
    }
    __builtin_amdgcn_s_setprio(0);
    __syncthreads();  // barrier drains lgkm+vmem: P reads done, next tiles ready
  }

  ushort_t* ch = ctx + (size_t)n * 65536;
#pragma unroll
  for (int dn = 0; dn < 4; ++dn)
#pragma unroll
    for (int r = 0; r < 4; ++r)
      ch[(size_t)(i0 + 4 * g + r) * 64 + dn * 16 + c] = f2bf(cacc[dn][r]);
#undef STAGE_K
#undef STAGE_V
#undef KFRAG
#undef VFRAG
}

// ---------------- residual + LayerNorm ----------------
__global__ __launch_bounds__(256) void ln_kernel(const float* __restrict__ proj,
                                                 const float* __restrict__ resid,
                                                 const float* __restrict__ gamma,
                                                 const float* __restrict__ beta,
                                                 float* __restrict__ out) {
  __shared__ float sred[4], ssred[4];
  const int row = blockIdx.x, t = threadIdx.x;
  const float4 pv = ((const float4*)(proj + (size_t)row * 1024))[t];
  const float4 rv = ((const float4*)(resid + (size_t)row * 1024))[t];
  float4 x;
  x.x = pv.x + rv.x; x.y = pv.y + rv.y; x.z = pv.z + rv.z; x.w = pv.w + rv.w;
  float s = x.x + x.y + x.z + x.w;
  float ss = x.x * x.x + x.y * x.y + x.z * x.z + x.w * x.w;
#pragma unroll
  for (int msk = 1; msk < 64; msk <<= 1) {
    s += __shfl_xor(s, msk);
    ss += __shfl_xor(ss, msk);
  }
  const int w = t >> 6, lane = t & 63;
  if (lane == 0) { sred[w] = s; ssred[w] = ss; }
  __syncthreads();
  s = sred[0] + sred[1] + sred[2] + sred[3];
  ss = ssred[0] + ssred[1] + ssred[2] + ssred[3];
  const float mu = s * (1.f / 1024.f);
  const float var = ss * (1.f / 1024.f) - mu * mu;
  const float rs = rsqrtf(var + 1e-5f);
  const float4 gm = ((const float4*)gamma)[t];
  const float4 bt = ((const float4*)beta)[t];
  float4 o;
  o.x = (x.x - mu) * rs * gm.x + bt.x;
  o.y = (x.y - mu) * rs * gm.y + bt.y;
  o.z = (x.z - mu) * rs * gm.z + bt.z;
  o.w = (x.w - mu) * rs * gm.w + bt.w;
  ((float4*)(out + (size_t)row * 1024))[t] = o;
}

extern "C" void kernel_launch(void* const* d_in, const int* in_sizes, int n_in,
                              void* d_out, int out_size, void* d_ws, size_t ws_size,
                              hipStream_t stream) {
  const float* key   = (const float*)d_in[0];
  const float* value = (const float*)d_in[1];
  const float* query = (const float*)d_in[2];
  const float* Wq = (const float*)d_in[3];  const float* bq = (const float*)d_in[4];
  const float* Wk = (const float*)d_in[5];  const float* bk = (const float*)d_in[6];
  const float* Wv = (const float*)d_in[7];  const float* bv = (const float*)d_in[8];
  const float* Wo = (const float*)d_in[9];  const float* bo = (const float*)d_in[10];
  const float* gamma = (const float*)d_in[11];
  const float* beta  = (const float*)d_in[12];

  char* ws = (char*)d_ws;
  ushort_t* q_   = (ushort_t*)(ws + 0);
  ushort_t* k_   = (ushort_t*)(ws + 16777216);
  ushort_t* vt_  = (ushort_t*)(ws + 33554432);
  ushort_t* ctx_ = (ushort_t*)(ws + 50331648);
  ushort_t* wo_  = (ushort_t*)(ws + 67108864);
  float*    proj_ = (float*)(ws + 0);  // aliases q_,k_ (dead after attention)

  char* o8 = (char*)d_out;
  float*    outp  = (float*)o8;
  float*    attnp = (float*)(o8 + 33554432);
  ushort_t* xq  = (ushort_t*)(o8 + 33554432);
  ushort_t* xk  = (ushort_t*)(o8 + 50331648);
  ushort_t* xv  = (ushort_t*)(o8 + 67108864);
  ushort_t* wq_ = (ushort_t*)(o8 + 83886080);
  ushort_t* wk_ = (ushort_t*)(o8 + 85983232);
  ushort_t* wv_ = (ushort_t*)(o8 + 88080384);
  ushort_t* v_  = (ushort_t*)(o8 + 90177536);

  const int n4x = 8192 * 1024 / 4;
  const int n4w = 1024 * 1024 / 4;
  cvt_kernel<<<n4x / 256, 256, 0, stream>>>(query, xq, n4x);
  cvt_kernel<<<n4x / 256, 256, 0, stream>>>(key,   xk, n4x);
  cvt_kernel<<<n4x / 256, 256, 0, stream>>>(value, xv, n4x);
  cvt_kernel<<<n4w / 256, 256, 0, stream>>>(Wq, wq_, n4w);
  cvt_kernel<<<n4w / 256, 256, 0, stream>>>(Wk, wk_, n4w);
  cvt_kernel<<<n4w / 256, 256, 0, stream>>>(Wv, wv_, n4w);
  cvt_kernel<<<n4w / 256, 256, 0, stream>>>(Wo, wo_, n4w);

  dim3 gg(8, 64);
  gemm_nt<1><<<gg, 256, 0, stream>>>(xq, wq_, bq, q_, 8192, 1024, 1024);
  gemm_nt<1><<<gg, 256, 0, stream>>>(xk, wk_, bk, k_, 8192, 1024, 1024);
  gemm_nt<1><<<gg, 256, 0, stream>>>(xv, wv_, bv, v_, 8192, 1024, 1024);

  transpose_v<<<dim3(16, 128), 256, 0, stream>>>(v_, vt_);

  attn_kernel<<<2048, 256, 0, stream>>>(q_, k_, vt_, attnp, ctx_);

  gemm_nt<0><<<gg, 256, 0, stream>>>(ctx_, wo_, bo, proj_, 8192, 1024, 1024);

  ln_kernel<<<8192, 256, 0, stream>>>(proj_, query, gamma, beta, outp);
}

// Round 5
// 361.336 us; speedup vs baseline: 1.7499x; 1.0864x over previous
//
#include <hip/hip_runtime.h>
#include <stdint.h>

typedef unsigned short ushort_t;
typedef __attribute__((ext_vector_type(8))) short s16x8;
typedef __attribute__((ext_vector_type(8))) unsigned short u16x8;
typedef __attribute__((ext_vector_type(4))) unsigned short u16x4;
typedef __attribute__((ext_vector_type(4))) float f32x4;

#define AS1C(p) ((const __attribute__((address_space(1))) void*)(p))
#define AS3(p)  ((__attribute__((address_space(3))) void*)(p))

// 0.5 (attention scale) * log2(e)  — baked into Wq/bq so softmax can use exp2
#define QSCALE 0.7213475204444817f

// hardware exp2 / log2 (v_exp_f32 = 2^x, v_log_f32 = log2 x)
#define EXP2F(x) __builtin_amdgcn_exp2f(x)
#define LOG2F(x) __builtin_amdgcn_logf(x)

// per-wave LDS fence: own-wave ds_write -> ds_read ordering without s_barrier
#define WAVE_LDS_FENCE()                                    \
  do {                                                      \
    asm volatile("s_waitcnt lgkmcnt(0)" ::: "memory");      \
    __builtin_amdgcn_sched_barrier(0);                      \
  } while (0)

// raw workgroup barrier, compiler-fenced on both sides (waits done explicitly)
#define SBAR()                                              \
  do {                                                      \
    __builtin_amdgcn_sched_barrier(0);                      \
    __builtin_amdgcn_s_barrier();                           \
    __builtin_amdgcn_sched_barrier(0);                      \
  } while (0)

__device__ __forceinline__ ushort_t f2bf(float f) {
  uint32_t u = __float_as_uint(f);
  u += 0x7fffu + ((u >> 16) & 1u);
  return (ushort_t)(u >> 16);
}
__device__ __forceinline__ float bf2f(ushort_t h) {
  return __uint_as_float(((uint32_t)h) << 16);
}

// ---------------- activations f32 -> bf16 (3 tensors, one launch) ----------------
__global__ __launch_bounds__(256) void cvt3_kernel(const float* __restrict__ s0,
                                                   const float* __restrict__ s1,
                                                   const float* __restrict__ s2,
                                                   ushort_t* __restrict__ dst) {
  const int y = blockIdx.y;
  const float* src = y == 0 ? s0 : (y == 1 ? s1 : s2);
  const int i = blockIdx.x * 256 + threadIdx.x;
  const float4 v = ((const float4*)src)[i];
  ushort4 o;
  o.x = f2bf(v.x); o.y = f2bf(v.y); o.z = f2bf(v.z); o.w = f2bf(v.w);
  ((ushort4*)(dst + (size_t)y * 8388608))[i] = o;
}

// ---------------- weights f32 -> bf16 (Wq scaled by QSCALE), one launch ----------------
__global__ __launch_bounds__(256) void cvtw_kernel(const float* __restrict__ w0,
                                                   const float* __restrict__ w1,
                                                   const float* __restrict__ w2,
                                                   const float* __restrict__ w3,
                                                   ushort_t* __restrict__ dqkv,
                                                   ushort_t* __restrict__ dwo) {
  const int y = blockIdx.y;
  const float* src = y == 0 ? w0 : (y == 1 ? w1 : (y == 2 ? w2 : w3));
  ushort_t* dst = y < 3 ? dqkv + (size_t)y * 1048576 : dwo;
  const float sc = y == 0 ? QSCALE : 1.0f;
  const int i = blockIdx.x * 256 + threadIdx.x;
  const float4 v = ((const float4*)src)[i];
  ushort4 o;
  o.x = f2bf(v.x * sc); o.y = f2bf(v.y * sc); o.z = f2bf(v.z * sc); o.w = f2bf(v.w * sc);
  ((ushort4*)dst)[i] = o;
}

// ---------------- concat bias (bq scaled) ----------------
__global__ __launch_bounds__(256) void biascat_kernel(const float* __restrict__ bq,
                                                      const float* __restrict__ bk,
                                                      const float* __restrict__ bv,
                                                      float* __restrict__ dst) {
  const int i = blockIdx.x * 256 + threadIdx.x;
  dst[i] = i < 1024 ? bq[i] * QSCALE : (i < 2048 ? bk[i - 1024] : bv[i - 2048]);
}

// ---------------- bf16 NT GEMM, M=8192, K=1024, 128x128 tile, BK=32 ----------------
// Double-buffered LDS, ONE barrier per K-step with explicit counted waits.
// Per-block operand select: sel = n0>>10 picks A/C (QKV fusion); B/bias use global n0.
template <int OUT_BF16>
__global__ __launch_bounds__(256) void gemm_nt(const ushort_t* __restrict__ A0,
                                               const ushort_t* __restrict__ A1,
                                               const ushort_t* __restrict__ A2,
                                               const ushort_t* __restrict__ B,
                                               const float* __restrict__ bias,
                                               void* __restrict__ C0,
                                               void* __restrict__ C1,
                                               void* __restrict__ C2) {
  __shared__ ushort_t As[2][128 * 32];
  __shared__ ushort_t Bs[2][128 * 32];
  const int tid = threadIdx.x;
  const int w = tid >> 6, lane = tid & 63, g = lane >> 4, c = lane & 15;
  const int wm = w >> 1, wn = w & 1;
  const int m0 = blockIdx.y * 128, n0 = blockIdx.x * 128;
  const int sel = n0 >> 10, nloc0 = n0 & 1023;
  const ushort_t* A = sel == 0 ? A0 : (sel == 1 ? A1 : A2);
  char* C = (char*)(sel == 0 ? C0 : (sel == 1 ? C1 : C2));
  f32x4 acc[4][4] = {};

  const int row0 = tid >> 2, col0 = (tid & 3) << 3;
  const int row1 = (256 + tid) >> 2, col1 = ((256 + tid) & 3) << 3;
  const int dst0 = (0 * 256 + w * 64) * 8, dst1 = (1 * 256 + w * 64) * 8;

#define G_STAGE(buf, k0_)                                                                  \
  do {                                                                                     \
    __builtin_amdgcn_global_load_lds(AS1C(&A[(size_t)(m0 + row0) * 1024 + (k0_) + col0]),  \
                                     AS3(&As[buf][dst0]), 16, 0, 0);                       \
    __builtin_amdgcn_global_load_lds(AS1C(&B[(size_t)(n0 + row0) * 1024 + (k0_) + col0]),  \
                                     AS3(&Bs[buf][dst0]), 16, 0, 0);                       \
    __builtin_amdgcn_global_load_lds(AS1C(&A[(size_t)(m0 + row1) * 1024 + (k0_) + col1]),  \
                                     AS3(&As[buf][dst1]), 16, 0, 0);                       \
    __builtin_amdgcn_global_load_lds(AS1C(&B[(size_t)(n0 + row1) * 1024 + (k0_) + col1]),  \
                                     AS3(&Bs[buf][dst1]), 16, 0, 0);                       \
  } while (0)

  G_STAGE(0, 0);
  asm volatile("s_waitcnt vmcnt(0)" ::: "memory");
  SBAR();
  for (int it = 0; it < 32; ++it) {
    const int cur = it & 1;
    if (it < 31) G_STAGE(cur ^ 1, 32 * (it + 1));
    s16x8 af[4], bfr[4];
#pragma unroll
    for (int mi = 0; mi < 4; ++mi)
      af[mi] = *(const s16x8*)&As[cur][(wm * 64 + mi * 16 + c) * 32 + g * 8];
#pragma unroll
    for (int ni = 0; ni < 4; ++ni)
      bfr[ni] = *(const s16x8*)&Bs[cur][(wn * 64 + ni * 16 + c) * 32 + g * 8];
    __builtin_amdgcn_s_setprio(1);
#pragma unroll
    for (int mi = 0; mi < 4; ++mi)
#pragma unroll
      for (int ni = 0; ni < 4; ++ni)
        acc[mi][ni] = __builtin_amdgcn_mfma_f32_16x16x32_bf16(af[mi], bfr[ni], acc[mi][ni], 0, 0, 0);
    __builtin_amdgcn_s_setprio(0);
    // next tile staged (vmcnt) + my frag reads retired (lgkm) before anyone overwrites
    asm volatile("s_waitcnt vmcnt(0) lgkmcnt(0)" ::: "memory");
    SBAR();
  }
#undef G_STAGE

#pragma unroll
  for (int ni = 0; ni < 4; ++ni) {
    const int nn = wn * 64 + ni * 16 + c;
    const float bv = bias[n0 + nn];
#pragma unroll
    for (int mi = 0; mi < 4; ++mi) {
#pragma unroll
      for (int rr = 0; rr < 4; ++rr) {
        const int m = m0 + wm * 64 + mi * 16 + g * 4 + rr;
        const float val = acc[mi][ni][rr] + bv;
        if (OUT_BF16)
          ((ushort_t*)C)[(size_t)m * 1024 + nloc0 + nn] = f2bf(val);
        else
          ((float*)C)[(size_t)m * 1024 + nloc0 + nn] = val;
      }
    }
  }
}

// ---------------- V transpose per head: vt[n][dh][i] = v[n][i][dh] ----------------
__global__ __launch_bounds__(256) void transpose_v(const ushort_t* __restrict__ v,
                                                   ushort_t* __restrict__ vt) {
  __shared__ ushort_t T[64][72];
  const int n = blockIdx.y, ib = blockIdx.x;
  const int t = threadIdx.x;
  {
    const int row = t >> 2, cb = (t & 3) << 4;
    const ushort_t* src = v + (size_t)n * 65536 + (size_t)(ib * 64 + row) * 64 + cb;
    *(u16x8*)&T[row][cb] = *(const u16x8*)src;
    *(u16x8*)&T[row][cb + 8] = *(const u16x8*)(src + 8);
  }
  __syncthreads();
  {
    const int dh = t >> 2, ibs = (t & 3) << 4;
    u16x8 a, b;
#pragma unroll
    for (int e = 0; e < 8; ++e) { a[e] = T[ibs + e][dh]; b[e] = T[ibs + 8 + e][dh]; }
    ushort_t* dst = vt + (size_t)n * 65536 + (size_t)dh * 1024 + ib * 64 + ibs;
    *(u16x8*)dst = a;
    *(u16x8*)(dst + 8) = b;
  }
}

// ---------------- attention ----------------
// XCD-swizzled grid; K/V double-buffered via global_load_lds (pre-swizzled src);
// counted vmcnt barriers (P-stores never drained in-loop); exp2 softmax
// (Q pre-scaled by 0.5*log2e).
__global__ __launch_bounds__(256) void attn_kernel(const ushort_t* __restrict__ q,
                                                   const ushort_t* __restrict__ k,
                                                   const ushort_t* __restrict__ vt,
                                                   float* __restrict__ attn,
                                                   ushort_t* __restrict__ ctx) {
  __shared__ ushort_t Kb[2][64 * 64];
  __shared__ ushort_t Vb[2][64 * 64];
  __shared__ ushort_t Pb[4][16 * 64];
  const int wg = blockIdx.x;
  const int idx = ((wg & 7) << 8) | (wg >> 3);  // XCD swizzle (bijective, 2048=8*256)
  const int n = idx >> 4, qb = idx & 15;
  const int tid = threadIdx.x, w = tid >> 6, lane = tid & 63, g = lane >> 4, c = lane & 15;
  const int i0 = qb * 64 + w * 16;
  const ushort_t* qh = q + (size_t)n * 65536;
  const char* khb = (const char*)(k + (size_t)n * 65536);
  const char* vhb = (const char*)(vt + (size_t)n * 65536);
  char* pwb = (char*)&Pb[w][0];

  const int r0 = w * 16 + (lane >> 3);
  const int csw = (((lane & 7) ^ (lane >> 3)) << 4);

#define STAGE_K(buf, jt_)                                                                   \
  do {                                                                                      \
    __builtin_amdgcn_global_load_lds(AS1C(khb + ((size_t)(jt_)*64 + r0) * 128 + csw),       \
                                     AS3(&Kb[buf][(w * 2 + 0) * 512]), 16, 0, 0);           \
    __builtin_amdgcn_global_load_lds(AS1C(khb + ((size_t)(jt_)*64 + r0 + 8) * 128 + csw),   \
                                     AS3(&Kb[buf][(w * 2 + 1) * 512]), 16, 0, 0);           \
  } while (0)
#define STAGE_V(buf, jt_)                                                                   \
  do {                                                                                      \
    __builtin_amdgcn_global_load_lds(AS1C(vhb + (size_t)r0 * 2048 + (jt_)*128 + csw),       \
                                     AS3(&Vb[buf][(w * 2 + 0) * 512]), 16, 0, 0);           \
    __builtin_amdgcn_global_load_lds(AS1C(vhb + (size_t)(r0 + 8) * 2048 + (jt_)*128 + csw), \
                                     AS3(&Vb[buf][(w * 2 + 1) * 512]), 16, 0, 0);           \
  } while (0)
#define KFRAG(buf, jn, h)                                                     \
  (*(const s16x8*)((const char*)&Kb[buf][0] +                                 \
                   (((((jn)*16 + c) * 128 + (h)*64 + g * 16)) ^ ((c & 7) << 4))))
#define VFRAG(buf, dn, ks_)                                                   \
  (*(const s16x8*)((const char*)&Vb[buf][0] +                                 \
                   (((((dn)*16 + c) * 128 + (ks_)*64 + g * 16)) ^ ((c & 7) << 4))))

  const s16x8 aq0 = *(const s16x8*)&qh[(i0 + c) * 64 + g * 8];
  const s16x8 aq1 = *(const s16x8*)&qh[(i0 + c) * 64 + 32 + g * 8];

  // ---- pass 1: lane-local online max+sum (exp2 domain) ----
  float m_p[4], l_p[4];
#pragma unroll
  for (int r = 0; r < 4; ++r) { m_p[r] = -1e30f; l_p[r] = 0.f; }

  STAGE_K(0, 0);
  asm volatile("s_waitcnt vmcnt(0)" ::: "memory");
  SBAR();
  for (int jt = 0; jt < 16; ++jt) {
    const int cur = jt & 1;
    if (jt < 15) STAGE_K(cur ^ 1, jt + 1);
    f32x4 s[4];
    __builtin_amdgcn_s_setprio(1);
#pragma unroll
    for (int jn = 0; jn < 4; ++jn) {
      f32x4 z = {0.f, 0.f, 0.f, 0.f};
      z = __builtin_amdgcn_mfma_f32_16x16x32_bf16(aq0, KFRAG(cur, jn, 0), z, 0, 0, 0);
      z = __builtin_amdgcn_mfma_f32_16x16x32_bf16(aq1, KFRAG(cur, jn, 1), z, 0, 0, 0);
      s[jn] = z;
    }
    __builtin_amdgcn_s_setprio(0);
#pragma unroll
    for (int r = 0; r < 4; ++r) {
      const float pm = fmaxf(fmaxf(s[0][r], s[1][r]), fmaxf(s[2][r], s[3][r]));
      const float mn = fmaxf(m_p[r], pm);
      l_p[r] = l_p[r] * EXP2F(m_p[r] - mn) + EXP2F(s[0][r] - mn) + EXP2F(s[1][r] - mn) +
               EXP2F(s[2][r] - mn) + EXP2F(s[3][r] - mn);
      m_p[r] = mn;
    }
    if (jt < 15) {
      asm volatile("s_waitcnt vmcnt(0) lgkmcnt(0)" ::: "memory");
      SBAR();
    }
  }

  // merge the 16 lanes of each row group
  float bias_r[4];
#pragma unroll
  for (int r = 0; r < 4; ++r) {
    float m = m_p[r], l = l_p[r];
#pragma unroll
    for (int mask = 1; mask < 16; mask <<= 1) {
      const float mo = __shfl_xor(m, mask);
      const float lo = __shfl_xor(l, mask);
      const float mn = fmaxf(m, mo);
      l = l * EXP2F(m - mn) + lo * EXP2F(mo - mn);
      m = mn;
    }
    bias_r[r] = m + LOG2F(l);  // p = exp2(s - bias)
  }

  // ---- pass 2 ----
  f32x4 cacc[4] = {};
  float* arow = attn + (size_t)n * 1048576;

  STAGE_K(0, 0);
  STAGE_V(0, 0);
  asm volatile("s_waitcnt vmcnt(0) lgkmcnt(0)" ::: "memory");
  SBAR();
  for (int jt = 0; jt < 16; ++jt) {
    const int cur = jt & 1;
    if (jt < 15) { STAGE_K(cur ^ 1, jt + 1); STAGE_V(cur ^ 1, jt + 1); }
    f32x4 s[4];
    __builtin_amdgcn_s_setprio(1);
#pragma unroll
    for (int jn = 0; jn < 4; ++jn) {
      f32x4 z = {0.f, 0.f, 0.f, 0.f};
      z = __builtin_amdgcn_mfma_f32_16x16x32_bf16(aq0, KFRAG(cur, jn, 0), z, 0, 0, 0);
      z = __builtin_amdgcn_mfma_f32_16x16x32_bf16(aq1, KFRAG(cur, jn, 1), z, 0, 0, 0);
      s[jn] = z;
    }
    __builtin_amdgcn_s_setprio(0);
    // write P tile (bf16, swizzled): row=4g+r, col=jn*16+c
#pragma unroll
    for (int jn = 0; jn < 4; ++jn) {
#pragma unroll
      for (int r = 0; r < 4; ++r) {
        const float p = EXP2F(s[jn][r] - bias_r[r]);
        const int row = 4 * g + r;
        const int A = (row << 7) + ((jn * 16 + c) << 1);
        *(ushort_t*)(pwb + (A ^ ((row & 7) << 4))) = f2bf(p);
      }
    }
    WAVE_LDS_FENCE();
    // PV first (MFMA pipe), then stores (latency flies across the barrier)
    __builtin_amdgcn_s_setprio(1);
#pragma unroll
    for (int ks = 0; ks < 2; ++ks) {
      const int A = (c << 7) + (ks << 6) + (g << 4);
      const s16x8 pa = *(const s16x8*)(pwb + (A ^ ((c & 7) << 4)));
#pragma unroll
      for (int dn = 0; dn < 4; ++dn)
        cacc[dn] = __builtin_amdgcn_mfma_f32_16x16x32_bf16(pa, VFRAG(cur, dn, ks), cacc[dn], 0, 0, 0);
    }
    __builtin_amdgcn_s_setprio(0);
#pragma unroll
    for (int e = 0; e < 4; ++e) {
      const int row = g + 4 * e;
      const int A = (row << 7) + (c << 3);
      const u16x4 hv = *(const u16x4*)(pwb + (A ^ ((row & 7) << 4)));
      f32x4 fv;
#pragma unroll
      for (int t2 = 0; t2 < 4; ++t2) fv[t2] = bf2f(hv[t2]);
      *(f32x4*)&arow[(size_t)(i0 + row) * 1024 + jt * 64 + c * 4] = fv;
    }
    if (jt < 15) {
      // staging (oldest 4) complete; the 4 P-stores stay in flight
      asm volatile("s_waitcnt vmcnt(4) lgkmcnt(0)" ::: "memory");
      SBAR();
    }
  }

  ushort_t* ch = ctx + (size_t)n * 65536;
#pragma unroll
  for (int dn = 0; dn < 4; ++dn)
#pragma unroll
    for (int r = 0; r < 4; ++r)
      ch[(size_t)(i0 + 4 * g + r) * 64 + dn * 16 + c] = f2bf(cacc[dn][r]);
#undef STAGE_K
#undef STAGE_V
#undef KFRAG
#undef VFRAG
}

// ---------------- residual + LayerNorm ----------------
__global__ __launch_bounds__(256) void ln_kernel(const float* __restrict__ proj,
                                                 const float* __restrict__ resid,
                                                 const float* __restrict__ gamma,
                                                 const float* __restrict__ beta,
                                                 float* __restrict__ out) {
  __shared__ float sred[4], ssred[4];
  const int row = blockIdx.x, t = threadIdx.x;
  const float4 pv = ((const float4*)(proj + (size_t)row * 1024))[t];
  const float4 rv = ((const float4*)(resid + (size_t)row * 1024))[t];
  float4 x;
  x.x = pv.x + rv.x; x.y = pv.y + rv.y; x.z = pv.z + rv.z; x.w = pv.w + rv.w;
  float s = x.x + x.y + x.z + x.w;
  float ss = x.x * x.x + x.y * x.y + x.z * x.z + x.w * x.w;
#pragma unroll
  for (int msk = 1; msk < 64; msk <<= 1) {
    s += __shfl_xor(s, msk);
    ss += __shfl_xor(ss, msk);
  }
  const int w = t >> 6, lane = t & 63;
  if (lane == 0) { sred[w] = s; ssred[w] = ss; }
  __syncthreads();
  s = sred[0] + sred[1] + sred[2] + sred[3];
  ss = ssred[0] + ssred[1] + ssred[2] + ssred[3];
  const float mu = s * (1.f / 1024.f);
  const float var = ss * (1.f / 1024.f) - mu * mu;
  const float rs = rsqrtf(var + 1e-5f);
  const float4 gm = ((const float4*)gamma)[t];
  const float4 bt = ((const float4*)beta)[t];
  float4 o;
  o.x = (x.x - mu) * rs * gm.x + bt.x;
  o.y = (x.y - mu) * rs * gm.y + bt.y;
  o.z = (x.z - mu) * rs * gm.z + bt.z;
  o.w = (x.w - mu) * rs * gm.w + bt.w;
  ((float4*)(out + (size_t)row * 1024))[t] = o;
}

extern "C" void kernel_launch(void* const* d_in, const int* in_sizes, int n_in,
                              void* d_out, int out_size, void* d_ws, size_t ws_size,
                              hipStream_t stream) {
  const float* key   = (const float*)d_in[0];
  const float* value = (const float*)d_in[1];
  const float* query = (const float*)d_in[2];
  const float* Wq = (const float*)d_in[3];  const float* bq = (const float*)d_in[4];
  const float* Wk = (const float*)d_in[5];  const float* bk = (const float*)d_in[6];
  const float* Wv = (const float*)d_in[7];  const float* bv = (const float*)d_in[8];
  const float* Wo = (const float*)d_in[9];  const float* bo = (const float*)d_in[10];
  const float* gamma = (const float*)d_in[11];
  const float* beta  = (const float*)d_in[12];

  char* ws = (char*)d_ws;
  ushort_t* q_   = (ushort_t*)(ws + 0);
  ushort_t* k_   = (ushort_t*)(ws + 16777216);
  ushort_t* vt_  = (ushort_t*)(ws + 33554432);
  ushort_t* ctx_ = (ushort_t*)(ws + 50331648);
  ushort_t* wo_  = (ushort_t*)(ws + 67108864);
  float*    proj_ = (float*)(ws + 0);  // aliases q_,k_ (dead after attention)

  char* o8 = (char*)d_out;
  float*    outp  = (float*)o8;
  float*    attnp = (float*)(o8 + 33554432);
  // scratch inside the (not-yet-written) attn region:
  ushort_t* xq   = (ushort_t*)(o8 + 33554432);   // query bf16
  ushort_t* xk   = (ushort_t*)(o8 + 50331648);   // key   bf16
  ushort_t* xv   = (ushort_t*)(o8 + 67108864);   // value bf16
  ushort_t* wqkv = (ushort_t*)(o8 + 83886080);   // concat [3072][1024] bf16
  ushort_t* v_   = (ushort_t*)(o8 + 90177536);
  float*    bqkv = (float*)(o8 + 106954752);     // concat bias [3072] f32

  cvt3_kernel<<<dim3(8192, 3), 256, 0, stream>>>(query, key, value, xq);
  cvtw_kernel<<<dim3(1024, 4), 256, 0, stream>>>(Wq, Wk, Wv, Wo, wqkv, wo_);
  biascat_kernel<<<12, 256, 0, stream>>>(bq, bk, bv, bqkv);

  // fused QKV projection: 1536 blocks
  gemm_nt<1><<<dim3(24, 64), 256, 0, stream>>>(xq, xk, xv, wqkv, bqkv, q_, k_, v_);

  transpose_v<<<dim3(16, 128), 256, 0, stream>>>(v_, vt_);

  attn_kernel<<<2048, 256, 0, stream>>>(q_, k_, vt_, attnp, ctx_);

  gemm_nt<0><<<dim3(8, 64), 256, 0, stream>>>(ctx_, ctx_, ctx_, wo_, bo, proj_, proj_, proj_);

  ln_kernel<<<8192, 256, 0, stream>>>(proj_, query, gamma, beta, outp);
}